// Round 3
// baseline (606.835 us; speedup 1.0000x reference)
//
#include <hip/hip_runtime.h>
#include <math.h>

#define N_ROWS   65536
#define K_EMB    1024
#define D_EMB    256

typedef __attribute__((ext_vector_type(8)))  short short8;
typedef __attribute__((ext_vector_type(4)))  short short4v;
typedef __attribute__((ext_vector_type(16))) float floatx16;

__device__ inline unsigned short f2bf(float f) {
    unsigned u = __float_as_uint(f);
    unsigned r = u + 0x7fffu + ((u >> 16) & 1u);
    return (unsigned short)(r >> 16);
}
__device__ inline float bf2f(unsigned short s) {
    return __uint_as_float(((unsigned)s) << 16);
}

// ---------------- prep: 0.5*||e||^2 + negated bf16 hi/lo codebook ----------------
__global__ __launch_bounds__(64)
void prep_e(const float* __restrict__ ew, float* __restrict__ half_esq,
            short* __restrict__ neg_hi, short* __restrict__ neg_lo)
{
    const int k = blockIdx.x;
    const int d = threadIdx.x;  // 64 threads, 4 elems each
    float4 v = *(const float4*)(ew + (size_t)k * D_EMB + d * 4);
    float s = v.x * v.x + v.y * v.y + v.z * v.z + v.w * v.w;
#pragma unroll
    for (int off = 32; off > 0; off >>= 1) s += __shfl_down(s, off);
    if (d == 0) half_esq[k] = 0.5f * s;

    float f[4] = {-v.x, -v.y, -v.z, -v.w};
    short4v h, l;
#pragma unroll
    for (int j = 0; j < 4; ++j) {
        unsigned short hh = f2bf(f[j]);
        h[j] = (short)hh;
        l[j] = (short)f2bf(f[j] - bf2f(hh));
    }
    *(short4v*)(neg_hi + (size_t)k * D_EMB + d * 4) = h;
    *(short4v*)(neg_lo + (size_t)k * D_EMB + d * 4) = l;
}

// ---------------- Phase A: MFMA argmin (bf16 hi/lo split, 3-pass) ----------------
// Block: 32 rows staged once into LDS (bf16 hi/lo, XOR-swizzled 16B chunks,
// 32 KB -> 5 blocks/CU). The 4 waves PARTITION the 1024 codes (256 each);
// cross-wave argmin combine at the end. e (negated) is the A operand streamed
// from L2 with depth-1 register prefetch; x is B from LDS.
// acc = 0.5*esq[code] - x.e  ==> per-row argmin over acc directly.
__global__ __launch_bounds__(256, 4)
void argmin_mfma(const float* __restrict__ x,
                 const short* __restrict__ neg_hi,
                 const short* __restrict__ neg_lo,
                 const float* __restrict__ half_esq,
                 int* __restrict__ indices)
{
    __shared__ short xs_hi[32 * 256];
    __shared__ short xs_lo[32 * 256];

    const int t  = threadIdx.x;
    const int r0 = blockIdx.x * 32;

    // ---- stage x: fp32 -> bf16 hi/lo, swizzled so frag reads are 4-way optimal ----
#pragma unroll
    for (int i = 0; i < 4; ++i) {
        int q   = i * 256 + t;   // [0,1024)
        int row = q >> 5;        // [0,32)
        int g8  = q & 31;        // 8-float group within row
        const float* gp = x + (size_t)(r0 + row) * D_EMB + g8 * 8;
        float4 a = *(const float4*)gp;
        float4 b = *(const float4*)(gp + 4);
        float f[8] = {a.x, a.y, a.z, a.w, b.x, b.y, b.z, b.w};
        short8 h8, l8;
#pragma unroll
        for (int j = 0; j < 8; ++j) {
            unsigned short hh = f2bf(f[j]);
            h8[j] = (short)hh;
            l8[j] = (short)f2bf(f[j] - bf2f(hh));
        }
        int off = row * 256 + ((g8 ^ (row & 7)) << 3);
        *(short8*)(xs_hi + off) = h8;
        *(short8*)(xs_lo + off) = l8;
    }
    __syncthreads();

    const int w    = t >> 6;     // wave id -> code quarter
    const int lane = t & 63;
    const int l31  = lane & 31;
    const int half = lane >> 5;
    const int key  = l31 & 7;    // swizzle key (row == l31)
    const short* bbase_h = xs_hi + l31 * 256;
    const short* bbase_l = xs_lo + l31 * 256;

    float mv = 3.4e38f;
    int   mi = 0;

    for (int cp = 0; cp < 4; ++cp) {
        const int c0 = w * 256 + cp * 64;
        const int c1 = c0 + 32;

        floatx16 acc0, acc1;
#pragma unroll
        for (int rq = 0; rq < 4; ++rq) {
            float4 e0 = *(const float4*)(half_esq + c0 + rq * 8 + half * 4);
            float4 e1 = *(const float4*)(half_esq + c1 + rq * 8 + half * 4);
            acc0[rq * 4 + 0] = e0.x; acc0[rq * 4 + 1] = e0.y;
            acc0[rq * 4 + 2] = e0.z; acc0[rq * 4 + 3] = e0.w;
            acc1[rq * 4 + 0] = e1.x; acc1[rq * 4 + 1] = e1.y;
            acc1[rq * 4 + 2] = e1.z; acc1[rq * 4 + 3] = e1.w;
        }

        const short* a0base_h = neg_hi + (size_t)(c0 + l31) * D_EMB + half * 8;
        const short* a0base_l = neg_lo + (size_t)(c0 + l31) * D_EMB + half * 8;
        const short* a1base_h = neg_hi + (size_t)(c1 + l31) * D_EMB + half * 8;
        const short* a1base_l = neg_lo + (size_t)(c1 + l31) * D_EMB + half * 8;

        // depth-1 software pipeline on the A fragments
        short8 pa0h = *(const short8*)(a0base_h);
        short8 pa0l = *(const short8*)(a0base_l);
        short8 pa1h = *(const short8*)(a1base_h);
        short8 pa1l = *(const short8*)(a1base_l);

#pragma unroll
        for (int kt = 0; kt < 16; ++kt) {
            short8 a0h = pa0h, a0l = pa0l, a1h = pa1h, a1l = pa1l;
            if (kt < 15) {
                pa0h = *(const short8*)(a0base_h + (kt + 1) * 16);
                pa0l = *(const short8*)(a0base_l + (kt + 1) * 16);
                pa1h = *(const short8*)(a1base_h + (kt + 1) * 16);
                pa1l = *(const short8*)(a1base_l + (kt + 1) * 16);
            }
            int coff = (((2 * kt + half) ^ key) << 3);
            short8 bh = *(const short8*)(bbase_h + coff);
            short8 bl = *(const short8*)(bbase_l + coff);
            acc0 = __builtin_amdgcn_mfma_f32_32x32x16_bf16(a0h, bh, acc0, 0, 0, 0);
            acc1 = __builtin_amdgcn_mfma_f32_32x32x16_bf16(a1h, bh, acc1, 0, 0, 0);
            acc0 = __builtin_amdgcn_mfma_f32_32x32x16_bf16(a0h, bl, acc0, 0, 0, 0);
            acc1 = __builtin_amdgcn_mfma_f32_32x32x16_bf16(a1h, bl, acc1, 0, 0, 0);
            acc0 = __builtin_amdgcn_mfma_f32_32x32x16_bf16(a0l, bh, acc0, 0, 0, 0);
            acc1 = __builtin_amdgcn_mfma_f32_32x32x16_bf16(a1l, bh, acc1, 0, 0, 0);
        }

        // fold: C row = code-in-tile = (r&3) + 8*(r>>2) + 4*half; col = x-row = l31
#pragma unroll
        for (int r = 0; r < 16; ++r) {
            int code0 = c0 + (r & 3) + ((r >> 2) << 3) + half * 4;
            float v0 = acc0[r];
            if (v0 < mv || (v0 == mv && code0 < mi)) { mv = v0; mi = code0; }
            int code1 = code0 + 32;
            float v1 = acc1[r];
            if (v1 < mv || (v1 == mv && code1 < mi)) { mv = v1; mi = code1; }
        }
    }

    // combine the two 32-lane halves (disjoint code subsets, same x-row)
    {
        float ov = __shfl_xor(mv, 32);
        int   oi = __shfl_xor(mi, 32);
        if (ov < mv || (ov == mv && oi < mi)) { mv = ov; mi = oi; }
    }

    // cross-wave (code-quarter) combine via LDS (xs reuse safe after barrier)
    __syncthreads();
    float* cmv = (float*)xs_hi;
    int*   cmi = (int*)xs_lo;
    if (half == 0) {
        int slot = w * 32 + l31;
        cmv[slot] = mv;
        cmi[slot] = mi;
    }
    __syncthreads();
    if (t < 32) {
        float bv = cmv[t];
        int   bi = cmi[t];
#pragma unroll
        for (int ww = 1; ww < 4; ++ww) {
            float v = cmv[ww * 32 + t];
            int   i = cmi[ww * 32 + t];
            if (v < bv || (v == bv && i < bi)) { bv = v; bi = i; }
        }
        indices[r0 + t] = bi;
    }
}

// ---------------- Phase B: quantize + loss partials + scatter stats ----------------
__global__ __launch_bounds__(256)
void quant_kernel(const float* __restrict__ x,
                  const float* __restrict__ ew,
                  const int* __restrict__ indices,
                  float* __restrict__ out_q,
                  float* __restrict__ dw,
                  int* __restrict__ counts,
                  double* __restrict__ loss_buckets)
{
    const int row = blockIdx.x;
    const int d   = threadIdx.x;
    const int idx = indices[row];  // wave-uniform
    const float xv = x[(size_t)row * D_EMB + d];
    const float qv = ew[(size_t)idx * D_EMB + d];
    out_q[(size_t)row * D_EMB + d] = xv + (qv - xv);  // straight-through == quantized
    const float diff = qv - xv;
    float s = diff * diff;
#pragma unroll
    for (int off = 32; off > 0; off >>= 1) s += __shfl_down(s, off);
    __shared__ float part[4];
    const int lane = d & 63, wv = d >> 6;
    if (lane == 0) part[wv] = s;
    __syncthreads();
    atomicAdd(&dw[(size_t)idx * D_EMB + d], xv);
    if (d == 0) {
        float tot = part[0] + part[1] + part[2] + part[3];
        atomicAdd(&loss_buckets[row & 255], (double)tot);
        atomicAdd(&counts[idx], 1);
    }
}

// ---------------- C1: scalars + cluster sizes (one block of 1024) ----------------
__global__ __launch_bounds__(1024)
void finalize_small(const float* __restrict__ ema_cs,
                    const int* __restrict__ counts,
                    const double* __restrict__ loss_buckets,
                    float* __restrict__ cs_ws,
                    float* __restrict__ out_loss,
                    float* __restrict__ out_perp,
                    float* __restrict__ out_ncs)
{
    __shared__ float  red[1024];
    __shared__ double redd[256];
    const int k = threadIdx.x;
    const float cnt = (float)counts[k];
    const float ncs = 0.99f * ema_cs[k] + 0.01f * cnt;
    out_ncs[k] = ncs;
    red[k] = ncs;
    __syncthreads();
    for (int off = 512; off > 0; off >>= 1) {
        if (k < off) red[k] += red[k + off];
        __syncthreads();
    }
    const float n = red[0];
    __syncthreads();
    cs_ws[k] = (ncs + 1e-5f) / (n + 1024.0f * 1e-5f) * n;

    const float p = cnt / 65536.0f;
    red[k] = p * logf(p + 1e-10f);
    if (k < 256) redd[k] = loss_buckets[k];
    __syncthreads();
    for (int off = 512; off > 0; off >>= 1) {
        if (k < off) red[k] += red[k + off];
        __syncthreads();
    }
    if (k == 0) out_perp[0] = expf(-red[0]);
    for (int off = 128; off > 0; off >>= 1) {
        if (k < off) redd[k] += redd[k + off];
        __syncthreads();
    }
    if (k == 0) out_loss[0] = (float)(0.25 * (redd[0] / 16777216.0));
}

// ---------------- C2: codebook update ----------------
__global__ __launch_bounds__(256)
void codebook_kernel(const float* __restrict__ ema_w,
                     const float* __restrict__ dw,
                     const float* __restrict__ cs_ws,
                     float* __restrict__ out_emb,
                     float* __restrict__ out_ema)
{
    const int k = blockIdx.x;
    const int d = threadIdx.x;
    const size_t o = (size_t)k * D_EMB + d;
    const float nev = 0.99f * ema_w[o] + 0.01f * dw[o];
    out_ema[o] = nev;
    out_emb[o] = nev / cs_ws[k];
}

extern "C" void kernel_launch(void* const* d_in, const int* in_sizes, int n_in,
                              void* d_out, int out_size, void* d_ws, size_t ws_size,
                              hipStream_t stream)
{
    const float* x       = (const float*)d_in[0];  // 32*2048*256
    const float* ew      = (const float*)d_in[1];  // 1024*256
    const float* ema_cs  = (const float*)d_in[2];  // 1024
    const float* ema_w   = (const float*)d_in[3];  // 1024*256

    float* out       = (float*)d_out;
    float* out_loss  = out;                         // [1]
    float* out_q     = out + 1;                     // [16777216]
    float* out_perp  = out + 1 + 16777216;          // [1]
    float* out_emb   = out_perp + 1;                // [262144]
    float* out_ncs   = out_emb + 262144;            // [1024]
    float* out_ema   = out_ncs + 1024;              // [262144]

    char* ws = (char*)d_ws;
    float*  dw           = (float*)(ws);             // 1,048,576 B
    int*    counts       = (int*)(ws + 1048576);     // 4,096 B
    double* loss_buckets = (double*)(ws + 1052672);  // 2,048 B
    float*  half_esq     = (float*)(ws + 1054720);   // 4,096 B
    float*  cs_ws        = (float*)(ws + 1058816);   // 4,096 B
    int*    indices      = (int*)(ws + 1062912);     // 262,144 B

    // scratch bf16 codebook tables live inside out_q (overwritten later by
    // quant_kernel). out+4 is 16B-aligned; 1 MB total, well inside 64 MB.
    short* neg_hi = (short*)(out + 4);               // 1024*256 shorts
    short* neg_lo = (short*)(out + 4 + 131072);      // 1024*256 shorts

    // zero the accumulators (dw + counts + loss buckets)
    hipMemsetAsync(ws, 0, 1054720, stream);

    prep_e<<<K_EMB, 64, 0, stream>>>(ew, half_esq, neg_hi, neg_lo);
    argmin_mfma<<<N_ROWS / 32, 256, 0, stream>>>(x, neg_hi, neg_lo, half_esq, indices);
    quant_kernel<<<N_ROWS, 256, 0, stream>>>(x, ew, indices, out_q, dw, counts, loss_buckets);
    finalize_small<<<1, 1024, 0, stream>>>(ema_cs, counts, loss_buckets, cs_ws,
                                           out_loss, out_perp, out_ncs);
    codebook_kernel<<<K_EMB, 256, 0, stream>>>(ema_w, dw, cs_ws, out_emb, out_ema);
}

// Round 4
// 482.212 us; speedup vs baseline: 1.2584x; 1.2584x over previous
//
#include <hip/hip_runtime.h>
#include <math.h>

#define N_ROWS   65536
#define K_EMB    1024
#define D_EMB    256

typedef __attribute__((ext_vector_type(8)))  short short8;
typedef __attribute__((ext_vector_type(4)))  short short4v;
typedef __attribute__((ext_vector_type(16))) float floatx16;

__device__ inline unsigned short f2bf(float f) {
    unsigned u = __float_as_uint(f);
    unsigned r = u + 0x7fffu + ((u >> 16) & 1u);
    return (unsigned short)(r >> 16);
}
__device__ inline float bf2f(unsigned short s) {
    return __uint_as_float(((unsigned)s) << 16);
}

// ---------------- prep: 0.5*||e||^2 + negated bf16 hi/lo codebook ----------------
__global__ __launch_bounds__(64)
void prep_e(const float* __restrict__ ew, float* __restrict__ half_esq,
            short* __restrict__ neg_hi, short* __restrict__ neg_lo)
{
    const int k = blockIdx.x;
    const int d = threadIdx.x;  // 64 threads, 4 elems each
    float4 v = *(const float4*)(ew + (size_t)k * D_EMB + d * 4);
    float s = v.x * v.x + v.y * v.y + v.z * v.z + v.w * v.w;
#pragma unroll
    for (int off = 32; off > 0; off >>= 1) s += __shfl_down(s, off);
    if (d == 0) half_esq[k] = 0.5f * s;

    float f[4] = {-v.x, -v.y, -v.z, -v.w};
    short4v h, l;
#pragma unroll
    for (int j = 0; j < 4; ++j) {
        unsigned short hh = f2bf(f[j]);
        h[j] = (short)hh;
        l[j] = (short)f2bf(f[j] - bf2f(hh));
    }
    *(short4v*)(neg_hi + (size_t)k * D_EMB + d * 4) = h;
    *(short4v*)(neg_lo + (size_t)k * D_EMB + d * 4) = l;
}

// ---------------- Phase A: MFMA argmin (bf16 hi/lo split, 3-pass) ----------------
// Block: 32 rows staged once into LDS (bf16 hi/lo, XOR-swizzled, 32 KB).
// 4 waves partition the 1024 codes (256 each). e (negated) is the A operand
// streamed from L2; x is B from LDS. NO explicit prefetch and NO tight
// launch_bounds cap: round-3 showed a 128-reg cap + AGPR slab => scratch
// spills (137 MB writes). (256,2) reproduces round-2's spill-free allocation
// (~88 arch VGPR + acc), giving ~4 blocks/CU with 32 KB LDS.
// acc = 0.5*esq[code] - x.e  ==> per-row argmin over acc directly.
__global__ __launch_bounds__(256, 2)
void argmin_mfma(const float* __restrict__ x,
                 const short* __restrict__ neg_hi,
                 const short* __restrict__ neg_lo,
                 const float* __restrict__ half_esq,
                 int* __restrict__ indices)
{
    __shared__ short xs_hi[32 * 256];
    __shared__ short xs_lo[32 * 256];

    const int t  = threadIdx.x;
    const int r0 = blockIdx.x * 32;

    // ---- stage x: fp32 -> bf16 hi/lo, swizzled so frag reads are 4-way optimal ----
#pragma unroll
    for (int i = 0; i < 4; ++i) {
        int q   = i * 256 + t;   // [0,1024)
        int row = q >> 5;        // [0,32)
        int g8  = q & 31;        // 8-float group within row
        const float* gp = x + (size_t)(r0 + row) * D_EMB + g8 * 8;
        float4 a = *(const float4*)gp;
        float4 b = *(const float4*)(gp + 4);
        float f[8] = {a.x, a.y, a.z, a.w, b.x, b.y, b.z, b.w};
        short8 h8, l8;
#pragma unroll
        for (int j = 0; j < 8; ++j) {
            unsigned short hh = f2bf(f[j]);
            h8[j] = (short)hh;
            l8[j] = (short)f2bf(f[j] - bf2f(hh));
        }
        int off = row * 256 + ((g8 ^ (row & 7)) << 3);
        *(short8*)(xs_hi + off) = h8;
        *(short8*)(xs_lo + off) = l8;
    }
    __syncthreads();

    const int w    = t >> 6;     // wave id -> code quarter
    const int lane = t & 63;
    const int l31  = lane & 31;
    const int half = lane >> 5;
    const int key  = l31 & 7;    // swizzle key (row == l31)
    const short* bbase_h = xs_hi + l31 * 256;
    const short* bbase_l = xs_lo + l31 * 256;

    float mv = 3.4e38f;
    int   mi = 0;

    for (int cp = 0; cp < 4; ++cp) {
        const int c0 = w * 256 + cp * 64;
        const int c1 = c0 + 32;

        floatx16 acc0, acc1;
#pragma unroll
        for (int rq = 0; rq < 4; ++rq) {
            float4 e0 = *(const float4*)(half_esq + c0 + rq * 8 + half * 4);
            float4 e1 = *(const float4*)(half_esq + c1 + rq * 8 + half * 4);
            acc0[rq * 4 + 0] = e0.x; acc0[rq * 4 + 1] = e0.y;
            acc0[rq * 4 + 2] = e0.z; acc0[rq * 4 + 3] = e0.w;
            acc1[rq * 4 + 0] = e1.x; acc1[rq * 4 + 1] = e1.y;
            acc1[rq * 4 + 2] = e1.z; acc1[rq * 4 + 3] = e1.w;
        }

        const short* a0base_h = neg_hi + (size_t)(c0 + l31) * D_EMB + half * 8;
        const short* a0base_l = neg_lo + (size_t)(c0 + l31) * D_EMB + half * 8;
        const short* a1base_h = neg_hi + (size_t)(c1 + l31) * D_EMB + half * 8;
        const short* a1base_l = neg_lo + (size_t)(c1 + l31) * D_EMB + half * 8;

#pragma unroll 4
        for (int kt = 0; kt < 16; ++kt) {
            int coff = (((2 * kt + half) ^ key) << 3);
            short8 bh = *(const short8*)(bbase_h + coff);
            short8 bl = *(const short8*)(bbase_l + coff);
            short8 a0h = *(const short8*)(a0base_h + kt * 16);
            short8 a0l = *(const short8*)(a0base_l + kt * 16);
            short8 a1h = *(const short8*)(a1base_h + kt * 16);
            short8 a1l = *(const short8*)(a1base_l + kt * 16);
            acc0 = __builtin_amdgcn_mfma_f32_32x32x16_bf16(a0h, bh, acc0, 0, 0, 0);
            acc1 = __builtin_amdgcn_mfma_f32_32x32x16_bf16(a1h, bh, acc1, 0, 0, 0);
            acc0 = __builtin_amdgcn_mfma_f32_32x32x16_bf16(a0h, bl, acc0, 0, 0, 0);
            acc1 = __builtin_amdgcn_mfma_f32_32x32x16_bf16(a1h, bl, acc1, 0, 0, 0);
            acc0 = __builtin_amdgcn_mfma_f32_32x32x16_bf16(a0l, bh, acc0, 0, 0, 0);
            acc1 = __builtin_amdgcn_mfma_f32_32x32x16_bf16(a1l, bh, acc1, 0, 0, 0);
        }

        // fold: C row = code-in-tile = (r&3) + 8*(r>>2) + 4*half; col = x-row = l31
#pragma unroll
        for (int r = 0; r < 16; ++r) {
            int code0 = c0 + (r & 3) + ((r >> 2) << 3) + half * 4;
            float v0 = acc0[r];
            if (v0 < mv || (v0 == mv && code0 < mi)) { mv = v0; mi = code0; }
            int code1 = code0 + 32;
            float v1 = acc1[r];
            if (v1 < mv || (v1 == mv && code1 < mi)) { mv = v1; mi = code1; }
        }
    }

    // combine the two 32-lane halves (disjoint code subsets, same x-row)
    {
        float ov = __shfl_xor(mv, 32);
        int   oi = __shfl_xor(mi, 32);
        if (ov < mv || (ov == mv && oi < mi)) { mv = ov; mi = oi; }
    }

    // cross-wave (code-quarter) combine via LDS (xs reuse safe after barrier)
    __syncthreads();
    float* cmv = (float*)xs_hi;
    int*   cmi = (int*)xs_lo;
    if (half == 0) {
        int slot = w * 32 + l31;
        cmv[slot] = mv;
        cmi[slot] = mi;
    }
    __syncthreads();
    if (t < 32) {
        float bv = cmv[t];
        int   bi = cmi[t];
#pragma unroll
        for (int ww = 1; ww < 4; ++ww) {
            float v = cmv[ww * 32 + t];
            int   i = cmi[ww * 32 + t];
            if (v < bv || (v == bv && i < bi)) { bv = v; bi = i; }
        }
        indices[r0 + t] = bi;
    }
}

// ---------------- Phase B1: quantized output + commitment loss ----------------
// 4 rows per block (1 wave per row), float4 lanes. Pure streaming; loss via
// 256 f64 buckets (65536 atomics total, negligible).
__global__ __launch_bounds__(256)
void quant_out(const float* __restrict__ x,
               const float* __restrict__ ew,
               const int* __restrict__ indices,
               float* __restrict__ out_q,
               double* __restrict__ loss_buckets)
{
    const int t    = threadIdx.x;
    const int row  = blockIdx.x * 4 + (t >> 6);
    const int lane = t & 63;
    const int idx  = indices[row];  // wave-uniform
    const float4 xv = *(const float4*)(x  + (size_t)row * D_EMB + lane * 4);
    const float4 ev = *(const float4*)(ew + (size_t)idx * D_EMB + lane * 4);
    float4 q;
    q.x = xv.x + (ev.x - xv.x);
    q.y = xv.y + (ev.y - xv.y);
    q.z = xv.z + (ev.z - xv.z);
    q.w = xv.w + (ev.w - xv.w);
    *(float4*)(out_q + (size_t)row * D_EMB + lane * 4) = q;
    float dx = ev.x - xv.x, dy = ev.y - xv.y, dz = ev.z - xv.z, dwv = ev.w - xv.w;
    float s = dx * dx + dy * dy + dz * dz + dwv * dwv;
#pragma unroll
    for (int off = 32; off > 0; off >>= 1) s += __shfl_down(s, off);
    if (lane == 0) atomicAdd(&loss_buckets[row & 255], (double)s);
}

// ---------------- Phase B2: per-code counts + dw (zero global atomics) ----------
// One block per code. Scan the 256 KB index array (L2-resident) in 2048-row
// chunks, compact matching row ids into LDS, then each thread (one dim) sums
// the gathered rows. Direct writes for dw/counts (no memset needed).
__global__ __launch_bounds__(256)
void code_stats(const float* __restrict__ x,
                const int* __restrict__ indices,
                float* __restrict__ dw,
                int* __restrict__ counts)
{
    __shared__ int rows[2048];
    __shared__ int nmatch;
    const int k = blockIdx.x;
    const int t = threadIdx.x;
    float sum = 0.0f;   // thread owns dim t
    int total = 0;

    for (int c = 0; c < N_ROWS; c += 2048) {
        if (t == 0) nmatch = 0;
        __syncthreads();
        const int base = c + t * 8;
        int4 a = *(const int4*)(indices + base);
        int4 b = *(const int4*)(indices + base + 4);
        int m[8] = {a.x, a.y, a.z, a.w, b.x, b.y, b.z, b.w};
#pragma unroll
        for (int j = 0; j < 8; ++j)
            if (m[j] == k) { int p = atomicAdd(&nmatch, 1); rows[p] = base + j; }
        __syncthreads();
        const int n = nmatch;
        total += n;
        for (int r = 0; r < n; ++r)
            sum += x[(size_t)rows[r] * D_EMB + t];
        __syncthreads();
    }
    dw[(size_t)k * D_EMB + t] = sum;
    if (t == 0) counts[k] = total;
}

// ---------------- C1: scalars + cluster sizes (one block of 1024) ----------------
__global__ __launch_bounds__(1024)
void finalize_small(const float* __restrict__ ema_cs,
                    const int* __restrict__ counts,
                    const double* __restrict__ loss_buckets,
                    float* __restrict__ cs_ws,
                    float* __restrict__ out_loss,
                    float* __restrict__ out_perp,
                    float* __restrict__ out_ncs)
{
    __shared__ float  red[1024];
    __shared__ double redd[256];
    const int k = threadIdx.x;
    const float cnt = (float)counts[k];
    const float ncs = 0.99f * ema_cs[k] + 0.01f * cnt;
    out_ncs[k] = ncs;
    red[k] = ncs;
    __syncthreads();
    for (int off = 512; off > 0; off >>= 1) {
        if (k < off) red[k] += red[k + off];
        __syncthreads();
    }
    const float n = red[0];
    __syncthreads();
    cs_ws[k] = (ncs + 1e-5f) / (n + 1024.0f * 1e-5f) * n;

    const float p = cnt / 65536.0f;
    red[k] = p * logf(p + 1e-10f);
    if (k < 256) redd[k] = loss_buckets[k];
    __syncthreads();
    for (int off = 512; off > 0; off >>= 1) {
        if (k < off) red[k] += red[k + off];
        __syncthreads();
    }
    if (k == 0) out_perp[0] = expf(-red[0]);
    for (int off = 128; off > 0; off >>= 1) {
        if (k < off) redd[k] += redd[k + off];
        __syncthreads();
    }
    if (k == 0) out_loss[0] = (float)(0.25 * (redd[0] / 16777216.0));
}

// ---------------- C2: codebook update ----------------
__global__ __launch_bounds__(256)
void codebook_kernel(const float* __restrict__ ema_w,
                     const float* __restrict__ dw,
                     const float* __restrict__ cs_ws,
                     float* __restrict__ out_emb,
                     float* __restrict__ out_ema)
{
    const int k = blockIdx.x;
    const int d = threadIdx.x;
    const size_t o = (size_t)k * D_EMB + d;
    const float nev = 0.99f * ema_w[o] + 0.01f * dw[o];
    out_ema[o] = nev;
    out_emb[o] = nev / cs_ws[k];
}

extern "C" void kernel_launch(void* const* d_in, const int* in_sizes, int n_in,
                              void* d_out, int out_size, void* d_ws, size_t ws_size,
                              hipStream_t stream)
{
    const float* x       = (const float*)d_in[0];  // 32*2048*256
    const float* ew      = (const float*)d_in[1];  // 1024*256
    const float* ema_cs  = (const float*)d_in[2];  // 1024
    const float* ema_w   = (const float*)d_in[3];  // 1024*256

    float* out       = (float*)d_out;
    float* out_loss  = out;                         // [1]
    float* out_q     = out + 1;                     // [16777216]
    float* out_perp  = out + 1 + 16777216;          // [1]
    float* out_emb   = out_perp + 1;                // [262144]
    float* out_ncs   = out_emb + 262144;            // [1024]
    float* out_ema   = out_ncs + 1024;              // [262144]

    char* ws = (char*)d_ws;
    float*  dw           = (float*)(ws);             // 1,048,576 B
    int*    counts       = (int*)(ws + 1048576);     // 4,096 B
    double* loss_buckets = (double*)(ws + 1052672);  // 2,048 B
    float*  half_esq     = (float*)(ws + 1054720);   // 4,096 B
    float*  cs_ws        = (float*)(ws + 1058816);   // 4,096 B
    int*    indices      = (int*)(ws + 1062912);     // 262,144 B

    // scratch bf16 codebook tables live inside out_q (overwritten by quant_out
    // AFTER argmin is done). out+4 is 16B-aligned; 1 MB total.
    short* neg_hi = (short*)(out + 4);               // 1024*256 shorts
    short* neg_lo = (short*)(out + 4 + 131072);      // 1024*256 shorts

    // only the loss buckets need zeroing now
    hipMemsetAsync(loss_buckets, 0, 2048, stream);

    prep_e<<<K_EMB, 64, 0, stream>>>(ew, half_esq, neg_hi, neg_lo);
    argmin_mfma<<<N_ROWS / 32, 256, 0, stream>>>(x, neg_hi, neg_lo, half_esq, indices);
    quant_out<<<N_ROWS / 4, 256, 0, stream>>>(x, ew, indices, out_q, loss_buckets);
    code_stats<<<K_EMB, 256, 0, stream>>>(x, indices, dw, counts);
    finalize_small<<<1, 1024, 0, stream>>>(ema_cs, counts, loss_buckets, cs_ws,
                                           out_loss, out_perp, out_ncs);
    codebook_kernel<<<K_EMB, 256, 0, stream>>>(ema_w, dw, cs_ws, out_emb, out_ema);
}

// Round 5
// 336.589 us; speedup vs baseline: 1.8029x; 1.4326x over previous
//
#include <hip/hip_runtime.h>
#include <math.h>

#define N_ROWS   65536
#define K_EMB    1024
#define D_EMB    256

typedef __attribute__((ext_vector_type(8)))  short short8;
typedef __attribute__((ext_vector_type(4)))  short short4v;
typedef __attribute__((ext_vector_type(16))) float floatx16;

__device__ inline unsigned short f2bf(float f) {
    unsigned u = __float_as_uint(f);
    unsigned r = u + 0x7fffu + ((u >> 16) & 1u);
    return (unsigned short)(r >> 16);
}
__device__ inline float bf2f(unsigned short s) {
    return __uint_as_float(((unsigned)s) << 16);
}

// ---------------- prep: 0.5*||e||^2 + negated bf16 hi/lo codebook ----------------
// Codebook is packed in MFMA A-fragment order:
//   pack[tile][kt][lane][j], tile=code>>5 (32 codes), kt=dim>>4 (16 dims),
//   lane=(code&31)+32*half, half=(dim&15)>>3, j=dim&7.
// A wave's fragment load is then 64 lanes x 16B CONTIGUOUS (1 KB), fixing the
// round-4 pathology (per-lane 512B-strided loads touching 32 lines/instr).
__global__ __launch_bounds__(64)
void prep_e(const float* __restrict__ ew, float* __restrict__ half_esq,
            short* __restrict__ pack_hi, short* __restrict__ pack_lo)
{
    const int k = blockIdx.x;
    const int t = threadIdx.x;  // 64 threads, 4 consecutive dims each
    float4 v = *(const float4*)(ew + (size_t)k * D_EMB + t * 4);
    float s = v.x * v.x + v.y * v.y + v.z * v.z + v.w * v.w;
#pragma unroll
    for (int off = 32; off > 0; off >>= 1) s += __shfl_down(s, off);
    if (t == 0) half_esq[k] = 0.5f * s;

    const int d0   = t * 4;
    const int tile = k >> 5;
    const int kt   = d0 >> 4;
    const int half = (d0 & 15) >> 3;
    const int lane = (k & 31) + 32 * half;
    const int j0   = d0 & 7;          // 0 or 4
    const int off  = tile * 8192 + kt * 512 + lane * 8 + j0;

    float f[4] = {-v.x, -v.y, -v.z, -v.w};
    short4v h, l;
#pragma unroll
    for (int j = 0; j < 4; ++j) {
        unsigned short hh = f2bf(f[j]);
        h[j] = (short)hh;
        l[j] = (short)f2bf(f[j] - bf2f(hh));
    }
    *(short4v*)(pack_hi + off) = h;
    *(short4v*)(pack_lo + off) = l;
}

// ---------------- Phase A: MFMA argmin (bf16 hi/lo split, 3-pass) ----------------
// Block: 32 rows staged once into LDS (bf16 hi/lo, XOR-swizzled, 32 KB).
// 4 waves partition the 1024 codes (256 each). e (negated, fragment-packed)
// is the A operand streamed from L2 with fully-coalesced 1 KB loads +
// depth-1 register prefetch; x is B from LDS.
// acc = 0.5*esq[code] - x.e  ==> per-row argmin over acc directly.
__global__ __launch_bounds__(256, 2)
void argmin_mfma(const float* __restrict__ x,
                 const short* __restrict__ pack_hi,
                 const short* __restrict__ pack_lo,
                 const float* __restrict__ half_esq,
                 int* __restrict__ indices)
{
    __shared__ short xs_hi[32 * 256];
    __shared__ short xs_lo[32 * 256];

    const int t  = threadIdx.x;
    const int r0 = blockIdx.x * 32;

    // ---- stage x: fp32 -> bf16 hi/lo, swizzled so frag reads are 4-way optimal ----
#pragma unroll
    for (int i = 0; i < 4; ++i) {
        int q   = i * 256 + t;   // [0,1024)
        int row = q >> 5;        // [0,32)
        int g8  = q & 31;        // 8-float group within row
        const float* gp = x + (size_t)(r0 + row) * D_EMB + g8 * 8;
        float4 a = *(const float4*)gp;
        float4 b = *(const float4*)(gp + 4);
        float f[8] = {a.x, a.y, a.z, a.w, b.x, b.y, b.z, b.w};
        short8 h8, l8;
#pragma unroll
        for (int j = 0; j < 8; ++j) {
            unsigned short hh = f2bf(f[j]);
            h8[j] = (short)hh;
            l8[j] = (short)f2bf(f[j] - bf2f(hh));
        }
        int off = row * 256 + ((g8 ^ (row & 7)) << 3);
        *(short8*)(xs_hi + off) = h8;
        *(short8*)(xs_lo + off) = l8;
    }
    __syncthreads();

    const int w    = t >> 6;     // wave id -> code quarter
    const int lane = t & 63;
    const int l31  = lane & 31;
    const int half = lane >> 5;
    const int key  = l31 & 7;    // swizzle key (row == l31)
    const short* bbase_h = xs_hi + l31 * 256;
    const short* bbase_l = xs_lo + l31 * 256;

    float mv = 3.4e38f;
    int   mi = 0;

    for (int cp = 0; cp < 4; ++cp) {
        const int c0 = w * 256 + cp * 64;
        const int c1 = c0 + 32;
        const int tile0 = c0 >> 5;   // tile1 = tile0+1

        floatx16 acc0, acc1;
#pragma unroll
        for (int rq = 0; rq < 4; ++rq) {
            float4 e0 = *(const float4*)(half_esq + c0 + rq * 8 + half * 4);
            float4 e1 = *(const float4*)(half_esq + c1 + rq * 8 + half * 4);
            acc0[rq * 4 + 0] = e0.x; acc0[rq * 4 + 1] = e0.y;
            acc0[rq * 4 + 2] = e0.z; acc0[rq * 4 + 3] = e0.w;
            acc1[rq * 4 + 0] = e1.x; acc1[rq * 4 + 1] = e1.y;
            acc1[rq * 4 + 2] = e1.z; acc1[rq * 4 + 3] = e1.w;
        }

        // fragment-packed bases: wave reads CONTIGUOUS 1 KB per load
        const short* p0h = pack_hi + tile0 * 8192 + lane * 8;
        const short* p0l = pack_lo + tile0 * 8192 + lane * 8;
        const short* p1h = p0h + 8192;
        const short* p1l = p0l + 8192;

        // depth-1 register prefetch ((256,2): no reg cap => no spills)
        short8 a0h = *(const short8*)(p0h);
        short8 a0l = *(const short8*)(p0l);
        short8 a1h = *(const short8*)(p1h);
        short8 a1l = *(const short8*)(p1l);

#pragma unroll 4
        for (int kt = 0; kt < 16; ++kt) {
            short8 n0h, n0l, n1h, n1l;
            if (kt < 15) {
                n0h = *(const short8*)(p0h + (kt + 1) * 512);
                n0l = *(const short8*)(p0l + (kt + 1) * 512);
                n1h = *(const short8*)(p1h + (kt + 1) * 512);
                n1l = *(const short8*)(p1l + (kt + 1) * 512);
            }
            int coff = (((2 * kt + half) ^ key) << 3);
            short8 bh = *(const short8*)(bbase_h + coff);
            short8 bl = *(const short8*)(bbase_l + coff);
            acc0 = __builtin_amdgcn_mfma_f32_32x32x16_bf16(a0h, bh, acc0, 0, 0, 0);
            acc1 = __builtin_amdgcn_mfma_f32_32x32x16_bf16(a1h, bh, acc1, 0, 0, 0);
            acc0 = __builtin_amdgcn_mfma_f32_32x32x16_bf16(a0h, bl, acc0, 0, 0, 0);
            acc1 = __builtin_amdgcn_mfma_f32_32x32x16_bf16(a1h, bl, acc1, 0, 0, 0);
            acc0 = __builtin_amdgcn_mfma_f32_32x32x16_bf16(a0l, bh, acc0, 0, 0, 0);
            acc1 = __builtin_amdgcn_mfma_f32_32x32x16_bf16(a1l, bh, acc1, 0, 0, 0);
            a0h = n0h; a0l = n0l; a1h = n1h; a1l = n1l;
        }

        // fold: C row = code-in-tile = (r&3) + 8*(r>>2) + 4*half; col = x-row = l31
#pragma unroll
        for (int r = 0; r < 16; ++r) {
            int code0 = c0 + (r & 3) + ((r >> 2) << 3) + half * 4;
            float v0 = acc0[r];
            if (v0 < mv || (v0 == mv && code0 < mi)) { mv = v0; mi = code0; }
            int code1 = code0 + 32;
            float v1 = acc1[r];
            if (v1 < mv || (v1 == mv && code1 < mi)) { mv = v1; mi = code1; }
        }
    }

    // combine the two 32-lane halves (disjoint code subsets, same x-row)
    {
        float ov = __shfl_xor(mv, 32);
        int   oi = __shfl_xor(mi, 32);
        if (ov < mv || (ov == mv && oi < mi)) { mv = ov; mi = oi; }
    }

    // cross-wave (code-quarter) combine via LDS (xs reuse safe after barrier)
    __syncthreads();
    float* cmv = (float*)xs_hi;
    int*   cmi = (int*)xs_lo;
    if (half == 0) {
        int slot = w * 32 + l31;
        cmv[slot] = mv;
        cmi[slot] = mi;
    }
    __syncthreads();
    if (t < 32) {
        float bv = cmv[t];
        int   bi = cmi[t];
#pragma unroll
        for (int ww = 1; ww < 4; ++ww) {
            float v = cmv[ww * 32 + t];
            int   i = cmi[ww * 32 + t];
            if (v < bv || (v == bv && i < bi)) { bv = v; bi = i; }
        }
        indices[r0 + t] = bi;
    }
}

// ---------------- Phase B1: quantized output + commitment loss ----------------
__global__ __launch_bounds__(256)
void quant_out(const float* __restrict__ x,
               const float* __restrict__ ew,
               const int* __restrict__ indices,
               float* __restrict__ out_q,
               double* __restrict__ loss_buckets)
{
    const int t    = threadIdx.x;
    const int row  = blockIdx.x * 4 + (t >> 6);
    const int lane = t & 63;
    const int idx  = indices[row];  // wave-uniform
    const float4 xv = *(const float4*)(x  + (size_t)row * D_EMB + lane * 4);
    const float4 ev = *(const float4*)(ew + (size_t)idx * D_EMB + lane * 4);
    float4 q;
    q.x = xv.x + (ev.x - xv.x);
    q.y = xv.y + (ev.y - xv.y);
    q.z = xv.z + (ev.z - xv.z);
    q.w = xv.w + (ev.w - xv.w);
    *(float4*)(out_q + (size_t)row * D_EMB + lane * 4) = q;
    float dx = ev.x - xv.x, dy = ev.y - xv.y, dz = ev.z - xv.z, dwv = ev.w - xv.w;
    float s = dx * dx + dy * dy + dz * dz + dwv * dwv;
#pragma unroll
    for (int off = 32; off > 0; off >>= 1) s += __shfl_down(s, off);
    if (lane == 0) atomicAdd(&loss_buckets[row & 255], (double)s);
}

// ---------------- Phase B2: per-code counts + dw (zero global atomics) ----------
__global__ __launch_bounds__(256)
void code_stats(const float* __restrict__ x,
                const int* __restrict__ indices,
                float* __restrict__ dw,
                int* __restrict__ counts)
{
    __shared__ int rows[2048];
    __shared__ int nmatch;
    const int k = blockIdx.x;
    const int t = threadIdx.x;
    float sum = 0.0f;   // thread owns dim t
    int total = 0;

    for (int c = 0; c < N_ROWS; c += 2048) {
        if (t == 0) nmatch = 0;
        __syncthreads();
        const int base = c + t * 8;
        int4 a = *(const int4*)(indices + base);
        int4 b = *(const int4*)(indices + base + 4);
        int m[8] = {a.x, a.y, a.z, a.w, b.x, b.y, b.z, b.w};
#pragma unroll
        for (int j = 0; j < 8; ++j)
            if (m[j] == k) { int p = atomicAdd(&nmatch, 1); rows[p] = base + j; }
        __syncthreads();
        const int n = nmatch;
        total += n;
        for (int r = 0; r < n; ++r)
            sum += x[(size_t)rows[r] * D_EMB + t];
        __syncthreads();
    }
    dw[(size_t)k * D_EMB + t] = sum;
    if (t == 0) counts[k] = total;
}

// ---------------- C1: scalars + cluster sizes (one block of 1024) ----------------
__global__ __launch_bounds__(1024)
void finalize_small(const float* __restrict__ ema_cs,
                    const int* __restrict__ counts,
                    const double* __restrict__ loss_buckets,
                    float* __restrict__ cs_ws,
                    float* __restrict__ out_loss,
                    float* __restrict__ out_perp,
                    float* __restrict__ out_ncs)
{
    __shared__ float  red[1024];
    __shared__ double redd[256];
    const int k = threadIdx.x;
    const float cnt = (float)counts[k];
    const float ncs = 0.99f * ema_cs[k] + 0.01f * cnt;
    out_ncs[k] = ncs;
    red[k] = ncs;
    __syncthreads();
    for (int off = 512; off > 0; off >>= 1) {
        if (k < off) red[k] += red[k + off];
        __syncthreads();
    }
    const float n = red[0];
    __syncthreads();
    cs_ws[k] = (ncs + 1e-5f) / (n + 1024.0f * 1e-5f) * n;

    const float p = cnt / 65536.0f;
    red[k] = p * logf(p + 1e-10f);
    if (k < 256) redd[k] = loss_buckets[k];
    __syncthreads();
    for (int off = 512; off > 0; off >>= 1) {
        if (k < off) red[k] += red[k + off];
        __syncthreads();
    }
    if (k == 0) out_perp[0] = expf(-red[0]);
    for (int off = 128; off > 0; off >>= 1) {
        if (k < off) redd[k] += redd[k + off];
        __syncthreads();
    }
    if (k == 0) out_loss[0] = (float)(0.25 * (redd[0] / 16777216.0));
}

// ---------------- C2: codebook update ----------------
__global__ __launch_bounds__(256)
void codebook_kernel(const float* __restrict__ ema_w,
                     const float* __restrict__ dw,
                     const float* __restrict__ cs_ws,
                     float* __restrict__ out_emb,
                     float* __restrict__ out_ema)
{
    const int k = blockIdx.x;
    const int d = threadIdx.x;
    const size_t o = (size_t)k * D_EMB + d;
    const float nev = 0.99f * ema_w[o] + 0.01f * dw[o];
    out_ema[o] = nev;
    out_emb[o] = nev / cs_ws[k];
}

extern "C" void kernel_launch(void* const* d_in, const int* in_sizes, int n_in,
                              void* d_out, int out_size, void* d_ws, size_t ws_size,
                              hipStream_t stream)
{
    const float* x       = (const float*)d_in[0];  // 32*2048*256
    const float* ew      = (const float*)d_in[1];  // 1024*256
    const float* ema_cs  = (const float*)d_in[2];  // 1024
    const float* ema_w   = (const float*)d_in[3];  // 1024*256

    float* out       = (float*)d_out;
    float* out_loss  = out;                         // [1]
    float* out_q     = out + 1;                     // [16777216]
    float* out_perp  = out + 1 + 16777216;          // [1]
    float* out_emb   = out_perp + 1;                // [262144]
    float* out_ncs   = out_emb + 262144;            // [1024]
    float* out_ema   = out_ncs + 1024;              // [262144]

    char* ws = (char*)d_ws;
    float*  dw           = (float*)(ws);             // 1,048,576 B
    int*    counts       = (int*)(ws + 1048576);     // 4,096 B
    double* loss_buckets = (double*)(ws + 1052672);  // 2,048 B
    float*  half_esq     = (float*)(ws + 1054720);   // 4,096 B
    float*  cs_ws        = (float*)(ws + 1058816);   // 4,096 B
    int*    indices      = (int*)(ws + 1062912);     // 262,144 B

    // fragment-packed bf16 codebook lives inside out_q (overwritten by
    // quant_out AFTER argmin is done). out+4 is 16B-aligned; 1 MB total.
    short* pack_hi = (short*)(out + 4);              // 1024*256 shorts
    short* pack_lo = (short*)(out + 4 + 131072);     // 1024*256 shorts

    // only the loss buckets need zeroing
    hipMemsetAsync(loss_buckets, 0, 2048, stream);

    prep_e<<<K_EMB, 64, 0, stream>>>(ew, half_esq, pack_hi, pack_lo);
    argmin_mfma<<<N_ROWS / 32, 256, 0, stream>>>(x, pack_hi, pack_lo, half_esq, indices);
    quant_out<<<N_ROWS / 4, 256, 0, stream>>>(x, ew, indices, out_q, loss_buckets);
    code_stats<<<K_EMB, 256, 0, stream>>>(x, indices, dw, counts);
    finalize_small<<<1, 1024, 0, stream>>>(ema_cs, counts, loss_buckets, cs_ws,
                                           out_loss, out_perp, out_ncs);
    codebook_kernel<<<K_EMB, 256, 0, stream>>>(ema_w, dw, cs_ws, out_emb, out_ema);
}